// Round 14
// baseline (298.712 us; speedup 1.0000x reference)
//
#include <hip/hip_runtime.h>
#include <hip/hip_bf16.h>
#include <math.h>

typedef __bf16 bf16;
typedef __attribute__((ext_vector_type(8))) __bf16 bf16x8;
typedef __attribute__((ext_vector_type(4))) __bf16 bf16x4;
typedef __attribute__((ext_vector_type(4))) float f32x4;

#define B_  16
#define S_  512
#define H_  768
#define NH_ 12
#define HD_ 64
#define A_  (B_*S_)   // 8192 token rows

// async global->LDS, 16B per lane; LDS dest = wave-uniform base + lane*16
__device__ __forceinline__ void gload_lds16(const void* g, void* l) {
  __builtin_amdgcn_global_load_lds((const __attribute__((address_space(1))) void*)g,
                                   (__attribute__((address_space(3))) void*)l, 16, 0, 0);
}

// fast gelu: 0.5x(1+tanh(.797885(x+.044715x^3))) = x*sigmoid(1.595769(x+.044715x^3))
// max |dev| vs exact erf-gelu ~3e-4 (absmax budget 0.102)
__device__ __forceinline__ float gelu_fast(float v) {
  const float u = 1.5957691216057308f * v * (1.0f + 0.044715f * v * v);
  const float e = __expf(-u);
  return v / (1.0f + e);
}

// =====================================================================================
// Double-buffered GEMM, SINGLE barrier per K-tile. BM=128, BN=192, BK=64.
// 512 threads = 8 waves (2M x 4N). 2 slots = 80KB LDS -> 2 blocks/CU.
// Stage(t+1) issued FIRST each tile (T3: max DMA flight time); all waves read slot t&1
// while DMA writes the other slot -> no intra-tile barriers. Boundary vmcnt(0)+barrier.
// SPLIT: 0 = full K; 1 = split-K/2 (slice = sw&1), partial fp32 -> outF (no bias).
// EPI 0: QKV scatter; EPI 2: gelu->bf16; EPI 4: +resB->bf16; EPI 5: fp32 partial (nt).
// =====================================================================================
template<int EPI, int SPLIT>
__global__ __launch_bounds__(512, 4) void k_gemm_db(
    const bf16* __restrict__ Amat, const bf16* __restrict__ Bt,
    const float* __restrict__ bias, const bf16* __restrict__ resB,
    bf16* __restrict__ outB, float* __restrict__ outF,
    bf16* __restrict__ outQ, bf16* __restrict__ outK, bf16* __restrict__ outVT,
    int M, int N, int Kstride)
{
  constexpr int BN_ = 192, NFRAG = 3, SLOT_E = 8192 + BN_*64, WN = 48;
  __shared__ __align__(16) bf16 LDS[2 * SLOT_E];   // 80 KB
  const int tid = threadIdx.x;
  const int w = tid >> 6, l = tid & 63;
  const int lr = l & 15, hi = l >> 4;
  const int wm = w >> 2, wn = w & 3;

  const int nbx = N / BN_;
  const int cpx = gridDim.x >> 3;
  const int sw  = (blockIdx.x & 7) * cpx + (blockIdx.x >> 3);
  const int tile  = sw >> SPLIT;
  const int slice = sw & ((1 << SPLIT) - 1);
  const int by = tile / nbx, bx = tile - by * nbx;
  const int row0 = by * 128, col0 = bx * BN_;
  const int Klen = Kstride >> SPLIT;
  const int koff = slice * Klen;
  const int NT = Klen / 64;

  auto stage = [&](int t, int u) {
    bf16* slot = LDS + (t & 1) * SLOT_E;
    if (u < 2) {
      const int fc = u*512 + tid;
      const int r = fc >> 3, s = fc & 7;
      const int gs = s ^ (r & 7);
      gload_lds16(Amat + (size_t)(row0 + r)*Kstride + koff + t*64 + gs*8,
                  slot + (size_t)fc*8 - (size_t)l*8);
    } else {
      const int fc = (u-2)*512 + tid;
      const int r = fc >> 3, s = fc & 7;
      const int gs = s ^ (r & 7);
      gload_lds16(Bt + (size_t)(col0 + r)*Kstride + koff + t*64 + gs*8,
                  slot + 8192 + (size_t)fc*8 - (size_t)l*8);
    }
  };

  f32x4 acc[4][NFRAG] = {};

#pragma unroll
  for (int u = 0; u < 5; ++u) stage(0, u);
  asm volatile("s_waitcnt vmcnt(0)" ::: "memory");
  __builtin_amdgcn_s_barrier();

  for (int t = 0; t < NT; ++t) {
    const bf16* slot = LDS + (t & 1) * SLOT_E;

    // ---- stage next tile FIRST (max DMA flight time under this tile's MFMA) ----
    if (t + 1 < NT) {
#pragma unroll
      for (int u = 0; u < 5; ++u) stage(t+1, u);
    }

    bf16x8 af[4], bfr[NFRAG];
    // ---- k-step 0 ----
#pragma unroll
    for (int m = 0; m < 4; ++m) {
      const int r = wm*64 + m*16 + lr;
      af[m] = *(const bf16x8*)(slot + r*64 + (hi ^ (r & 7))*8);
    }
#pragma unroll
    for (int n = 0; n < NFRAG; ++n) {
      const int r = wn*WN + n*16 + lr;
      bfr[n] = *(const bf16x8*)(slot + 8192 + r*64 + (hi ^ (r & 7))*8);
    }
    asm volatile("s_waitcnt lgkmcnt(0)" ::: "memory");
    __builtin_amdgcn_sched_barrier(0);
    __builtin_amdgcn_s_setprio(1);
#pragma unroll
    for (int m = 0; m < 4; ++m)
#pragma unroll
      for (int n = 0; n < NFRAG; ++n)
        acc[m][n] = __builtin_amdgcn_mfma_f32_16x16x32_bf16(af[m], bfr[n], acc[m][n], 0, 0, 0);
    __builtin_amdgcn_s_setprio(0);

    // ---- k-step 1 ----
#pragma unroll
    for (int m = 0; m < 4; ++m) {
      const int r = wm*64 + m*16 + lr;
      af[m] = *(const bf16x8*)(slot + r*64 + ((4 + hi) ^ (r & 7))*8);
    }
#pragma unroll
    for (int n = 0; n < NFRAG; ++n) {
      const int r = wn*WN + n*16 + lr;
      bfr[n] = *(const bf16x8*)(slot + 8192 + r*64 + ((4 + hi) ^ (r & 7))*8);
    }
    asm volatile("s_waitcnt lgkmcnt(0)" ::: "memory");
    __builtin_amdgcn_sched_barrier(0);
    __builtin_amdgcn_s_setprio(1);
#pragma unroll
    for (int m = 0; m < 4; ++m)
#pragma unroll
      for (int n = 0; n < NFRAG; ++n)
        acc[m][n] = __builtin_amdgcn_mfma_f32_16x16x32_bf16(af[m], bfr[n], acc[m][n], 0, 0, 0);
    __builtin_amdgcn_s_setprio(0);

    // ---- single boundary barrier per tile ----
    if (t < NT - 1) {
      asm volatile("s_waitcnt vmcnt(0)" ::: "memory");
      __builtin_amdgcn_s_barrier();
    }
  }

  // ---- epilogue ----
#pragma unroll
  for (int m = 0; m < 4; ++m) {
#pragma unroll
    for (int n = 0; n < NFRAG; ++n) {
#pragma unroll
      for (int i = 0; i < 4; ++i) {
        const int row = row0 + wm*64 + m*16 + hi*4 + i;
        const int col = col0 + wn*WN + n*16 + lr;
        if constexpr (EPI == 5) {
          __builtin_nontemporal_store(acc[m][n][i],
              outF + (size_t)slice*M*N + (size_t)row*N + col);
        } else if constexpr (EPI == 2) {
          float v = acc[m][n][i] + bias[col];
          outB[(size_t)row*N + col] = (bf16)gelu_fast(v);
        } else if constexpr (EPI == 4) {
          float v = acc[m][n][i] + bias[col];
          v += (float)resB[(size_t)row*N + col];
          outB[(size_t)row*N + col] = (bf16)v;
        } else {
          float v = acc[m][n][i] + bias[col];
          const int b = row >> 9, s = row & 511;
          const int which = col / H_;
          const int hcol = col - which * H_;
          const int h = hcol >> 6, d = hcol & 63;
          const size_t bh = (size_t)b * NH_ + h;
          if (which == 0)      outQ[(bh*S_ + s)*HD_ + d] = (bf16)v;
          else if (which == 1) outK[(bh*S_ + s)*HD_ + d] = (bf16)v;
          else                 outVT[(bh*HD_ + d)*S_ + s] = (bf16)v;
        }
      }
    }
  }
}

// ---------------- fused attention (R11 ordering): P stored before PV-sync -----------
__global__ __launch_bounds__(256) void k_attn_fused(
    const bf16* __restrict__ Qm, const bf16* __restrict__ Km, const bf16* __restrict__ VT,
    const unsigned char* __restrict__ mask, float* __restrict__ P, bf16* __restrict__ AO)
{
  __shared__ __align__(16) bf16 KVs[512*64];
  const int tid = threadIdx.x, w = tid >> 6, l = tid & 63;
  const int lr = l & 15, hi = l >> 4;
  const int cpx = gridDim.x >> 3;
  const int sw  = (blockIdx.x & 7) * cpx + (blockIdx.x >> 3);
  const int bh = sw >> 3, qt = sw & 7;
  const int b = bh / NH_, h = bh - b * NH_;
  const int swz = (lr & 7) << 4;

  const bf16* Kg = Km + (size_t)bh * S_ * HD_;
#pragma unroll
  for (int rnd = 0; rnd < 16; ++rnd) {
    const int c = rnd*256 + tid;
    const int row = c >> 3, col16 = (c & 7) ^ (row & 7);
    gload_lds16(Kg + row*HD_ + col16*8, KVs + (rnd*4 + w)*512);
  }
  const bf16* qrow_g = Qm + (size_t)bh * S_ * HD_ + (size_t)(qt*64 + w*16 + lr) * HD_;
  bf16x8 qf0 = *(const bf16x8*)(qrow_g + hi*8);
  bf16x8 qf1 = *(const bf16x8*)(qrow_g + 32 + hi*8);
  __syncthreads();

  f32x4 acc[32];
#pragma unroll
  for (int ct = 0; ct < 32; ++ct) acc[ct] = f32x4{0.f,0.f,0.f,0.f};
#pragma unroll
  for (int ct = 0; ct < 32; ++ct) {
    const char* kb = (const char*)(KVs + (ct*16 + lr)*64);
    bf16x8 a0 = *(const bf16x8*)(kb + ((hi*16) ^ swz));
    bf16x8 a1 = *(const bf16x8*)(kb + ((64 + hi*16) ^ swz));
    acc[ct] = __builtin_amdgcn_mfma_f32_16x16x32_bf16(a0, qf0, acc[ct], 0, 0, 0);
    acc[ct] = __builtin_amdgcn_mfma_f32_16x16x32_bf16(a1, qf1, acc[ct], 0, 0, 0);
  }
  __syncthreads();

  const bf16* Vg = VT + (size_t)bh * HD_ * S_;
#pragma unroll
  for (int rnd = 0; rnd < 16; ++rnd) {
    const int c = rnd*256 + tid;
    const int row = c >> 6, col16 = (c & 63) ^ (row & 7);
    gload_lds16(Vg + row*S_ + col16*8, KVs + (rnd*4 + w)*512);
  }

  const unsigned char* mrow = mask + b * S_;
  float mx = -1e30f;
#pragma unroll
  for (int ct = 0; ct < 32; ++ct) {
    const unsigned mk4 = *(const unsigned*)(mrow + ct*16 + hi*4);
#pragma unroll
    for (int i = 0; i < 4; ++i) {
      float v = acc[ct][i] * 0.125f;
      if ((mk4 >> (8*i)) & 0xff) v = -1e30f;
      acc[ct][i] = v;
      mx = fmaxf(mx, v);
    }
  }
  mx = fmaxf(mx, __shfl_xor(mx, 16));
  mx = fmaxf(mx, __shfl_xor(mx, 32));
  float sum = 0.f;
#pragma unroll
  for (int ct = 0; ct < 32; ++ct)
#pragma unroll
    for (int i = 0; i < 4; ++i) { float e = __expf(acc[ct][i] - mx); acc[ct][i] = e; sum += e; }
  sum += __shfl_xor(sum, 16);
  sum += __shfl_xor(sum, 32);
  const float inv = 1.f / sum;

  float* prow = P + ((size_t)bh*S_ + (size_t)qt*64 + w*16 + lr) * S_;
#pragma unroll
  for (int ct = 0; ct < 32; ++ct) {
#pragma unroll
    for (int i = 0; i < 4; ++i) acc[ct][i] *= inv;
    __builtin_nontemporal_store(acc[ct], (f32x4*)(prow + ct*16 + hi*4));
  }
  __syncthreads();   // V staged (drains V DMAs; P stores proceed in background)

  f32x4 o[4] = {};
#pragma unroll
  for (int c = 0; c < 16; ++c) {
    bf16x8 pa;
#pragma unroll
    for (int i = 0; i < 4; ++i) { pa[i] = (bf16)acc[2*c][i]; pa[4+i] = (bf16)acc[2*c+1][i]; }
    const int cb0 = (64*c + 8*hi) ^ swz;
    const int cb1 = (64*c + 32 + 8*hi) ^ swz;
#pragma unroll
    for (int nt = 0; nt < 4; ++nt) {
      const char* vb = (const char*)(KVs + (nt*16 + lr)*512);
      bf16x4 v0 = *(const bf16x4*)(vb + cb0);
      bf16x4 v1 = *(const bf16x4*)(vb + cb1);
      bf16x8 vf = {v0[0],v0[1],v0[2],v0[3], v1[0],v1[1],v1[2],v1[3]};
      o[nt] = __builtin_amdgcn_mfma_f32_16x16x32_bf16(pa, vf, o[nt], 0, 0, 0);
    }
  }

  bf16* aorow = AO + ((size_t)(b*S_ + qt*64 + w*16))*H_ + h*HD_;
#pragma unroll
  for (int nt = 0; nt < 4; ++nt)
#pragma unroll
    for (int i = 0; i < 4; ++i)
      aorow[(size_t)(hi*4 + i)*H_ + nt*16 + lr] = (bf16)o[nt][i];
}

// ---------------- LayerNorm over H=768 (bf16 input): one wave per row ---------------
__global__ __launch_bounds__(256) void k_layernorm(
    const bf16* __restrict__ X, const float* __restrict__ g, const float* __restrict__ bta,
    bf16* __restrict__ outB)
{
  const int w = threadIdx.x >> 6, l = threadIdx.x & 63;
  const int row = blockIdx.x * 4 + w;
  const bf16* x = X + (size_t)row * H_;
  float v[12]; float s = 0.f, ss = 0.f;
#pragma unroll
  for (int j = 0; j < 3; ++j) {
    bf16x4 b4 = *(const bf16x4*)(x + l*4 + j*256);
#pragma unroll
    for (int e = 0; e < 4; ++e) {
      const float f = (float)b4[e];
      v[j*4 + e] = f; s += f; ss += f*f;
    }
  }
#pragma unroll
  for (int d = 1; d < 64; d <<= 1) { s += __shfl_xor(s, d); ss += __shfl_xor(ss, d); }
  const float mean = s * (1.f / H_);
  const float var  = ss * (1.f / H_) - mean * mean;
  const float inv  = rsqrtf(var + 1e-5f);
#pragma unroll
  for (int j = 0; j < 3; ++j) {
    const int c = l*4 + j*256;
    const float4 gv = *(const float4*)(g + c);
    const float4 bv = *(const float4*)(bta + c);
    bf16x4 o;
    o[0] = (bf16)((v[j*4+0] - mean)*inv*gv.x + bv.x);
    o[1] = (bf16)((v[j*4+1] - mean)*inv*gv.y + bv.y);
    o[2] = (bf16)((v[j*4+2] - mean)*inv*gv.z + bv.z);
    o[3] = (bf16)((v[j*4+3] - mean)*inv*gv.w + bv.w);
    *(bf16x4*)(outB + (size_t)row*H_ + c) = o;
  }
}

// ---------------- fused split-K reduce + bias + residual + LayerNorm -> xout --------
__global__ __launch_bounds__(256) void k_ln_ffn2(
    const float* __restrict__ p0, const float* __restrict__ p1,
    const float* __restrict__ b2, const bf16* __restrict__ res,
    const float* __restrict__ g, const float* __restrict__ bta,
    float* __restrict__ xout)
{
  const int w = threadIdx.x >> 6, l = threadIdx.x & 63;
  const int row = blockIdx.x * 4 + w;
  const size_t base = (size_t)row * H_;
  float v[12]; float s = 0.f, ss = 0.f;
#pragma unroll
  for (int j = 0; j < 3; ++j) {
    const int c = l*4 + j*256;
    const float4 a0 = *(const float4*)(p0 + base + c);
    const float4 a1 = *(const float4*)(p1 + base + c);
    const float4 bb = *(const float4*)(b2 + c);
    bf16x4 r4 = *(const bf16x4*)(res + base + c);
    v[j*4+0] = a0.x + a1.x + bb.x + (float)r4[0];
    v[j*4+1] = a0.y + a1.y + bb.y + (float)r4[1];
    v[j*4+2] = a0.z + a1.z + bb.z + (float)r4[2];
    v[j*4+3] = a0.w + a1.w + bb.w + (float)r4[3];
#pragma unroll
    for (int e = 0; e < 4; ++e) { s += v[j*4+e]; ss += v[j*4+e]*v[j*4+e]; }
  }
#pragma unroll
  for (int d = 1; d < 64; d <<= 1) { s += __shfl_xor(s, d); ss += __shfl_xor(ss, d); }
  const float mean = s * (1.f / H_);
  const float var  = ss * (1.f / H_) - mean * mean;
  const float inv  = rsqrtf(var + 1e-5f);
#pragma unroll
  for (int j = 0; j < 3; ++j) {
    const int c = l*4 + j*256;
    const float4 gv = *(const float4*)(g + c);
    const float4 bv = *(const float4*)(bta + c);
    f32x4 y;
    y[0] = (v[j*4+0] - mean)*inv*gv.x + bv.x;
    y[1] = (v[j*4+1] - mean)*inv*gv.y + bv.y;
    y[2] = (v[j*4+2] - mean)*inv*gv.z + bv.z;
    y[3] = (v[j*4+3] - mean)*inv*gv.w + bv.w;
    __builtin_nontemporal_store(y, (f32x4*)(xout + base + c));
  }
}

// ---------------- fused fp32 -> bf16 conversions (5 segments, 1 kernel) -------------
#define NB0 (A_*H_/1024)      // 6144
#define NB1 (3*H_*H_/1024)    // 1728
#define NB2 (H_*H_/1024)      // 576
#define NB3 (4*H_*H_/1024)    // 2304
#define NB4 (4*H_*H_/1024)    // 2304
__global__ void k_conv_all(
    const float* __restrict__ s0, bf16* __restrict__ d0,
    const float* __restrict__ s1, bf16* __restrict__ d1,
    const float* __restrict__ s2, bf16* __restrict__ d2,
    const float* __restrict__ s3, bf16* __restrict__ d3,
    const float* __restrict__ s4, bf16* __restrict__ d4)
{
  int b = blockIdx.x;
  const float* src; bf16* dst;
  if      (b < NB0)                   { src = s0; dst = d0; }
  else if ((b -= NB0) < NB1)          { src = s1; dst = d1; }
  else if ((b -= NB1) < NB2)          { src = s2; dst = d2; }
  else if ((b -= NB2) < NB3)          { src = s3; dst = d3; }
  else    { b -= NB3;                   src = s4; dst = d4; }
  const int i = (b * 256 + threadIdx.x) * 4;
  const float4 vv = *(const float4*)(src + i);
  bf16x4 o; o[0]=(bf16)vv.x; o[1]=(bf16)vv.y; o[2]=(bf16)vv.z; o[3]=(bf16)vv.w;
  *(bf16x4*)(dst + i) = o;
}

extern "C" void kernel_launch(void* const* d_in, const int* in_sizes, int n_in,
                              void* d_out, int out_size, void* d_ws, size_t ws_size,
                              hipStream_t stream) {
  const float* x      = (const float*)d_in[0];
  const unsigned char* mask = (const unsigned char*)d_in[1];
  const float* w_qkv  = (const float*)d_in[2];
  const float* b_qkv  = (const float*)d_in[3];
  const float* w_out  = (const float*)d_in[4];
  const float* b_out  = (const float*)d_in[5];
  const float* w1     = (const float*)d_in[6];
  const float* b1     = (const float*)d_in[7];
  const float* w2     = (const float*)d_in[8];
  const float* b2     = (const float*)d_in[9];
  const float* ln1g   = (const float*)d_in[10];
  const float* ln1b   = (const float*)d_in[11];
  const float* ln2g   = (const float*)d_in[12];
  const float* ln2b   = (const float*)d_in[13];

  float* xout = (float*)d_out;                      // [8192, 768]
  float* P    = xout + (size_t)A_ * H_;             // [192, 512, 512] attn weights

  char* ws = (char*)d_ws;
  size_t off = 0;
  auto alloc = [&](size_t bytes) { char* p = ws + off; off += (bytes + 255) & ~255ull; return p; };

  bf16* xb   = (bf16*)alloc((size_t)A_*H_*2);
  bf16* wqkv = (bf16*)alloc((size_t)3*H_*H_*2);
  bf16* wo   = (bf16*)alloc((size_t)H_*H_*2);
  bf16* w1b  = (bf16*)alloc((size_t)4*H_*H_*2);
  bf16* w2b  = (bf16*)alloc((size_t)4*H_*H_*2);
  char* qreg = alloc((size_t)A_*H_*2*4);               // q | k | vt | ao
  bf16* q  = (bf16*)qreg;
  bf16* kb = q  + (size_t)A_*H_;
  bf16* vt = kb + (size_t)A_*H_;
  bf16* ao = vt + (size_t)A_*H_;
  bf16* hbuf = q;                                      // [8192,3072] alias, live after ao consumed
  bf16* y1b = (bf16*)alloc((size_t)A_*H_*2);
  bf16* x1b = (bf16*)alloc((size_t)A_*H_*2);
  float* part = (float*)alloc((size_t)2*A_*H_*4);      // split-K partials (fp32 x2)

  // fused conversions (one kernel)
  k_conv_all<<<NB0+NB1+NB2+NB3+NB4, 256, 0, stream>>>(
      x, xb, w_qkv, wqkv, w_out, wo, w1, w1b, w2, w2b);

  // QKV projection + scatter: BM=128, dbuf, 768 blocks
  k_gemm_db<0,0><<<(A_/128)*(3*H_/192), 512, 0, stream>>>(xb, wqkv, b_qkv, nullptr,
      nullptr, nullptr, q, kb, vt, A_, 3*H_, H_);
  // fused scores + softmax (P -> d_out, nt, pre-sync) + PV -> attn_out (XCD-grouped)
  k_attn_fused<<<B_*NH_*8, 256, 0, stream>>>(q, kb, vt, mask, P, ao);
  // out_proj + residual(xb) -> y1b bf16: BM=128, 256 blocks
  k_gemm_db<4,0><<<(A_/128)*(H_/192), 512, 0, stream>>>(ao, wo, b_out, xb,
      y1b, nullptr, nullptr, nullptr, nullptr, A_, H_, H_);
  k_layernorm<<<A_/4, 256, 0, stream>>>(y1b, ln1g, ln1b, x1b);
  // FFN1 + fast-gelu: BM=128, dbuf, 1024 blocks
  k_gemm_db<2,0><<<(A_/128)*(4*H_/192), 512, 0, stream>>>(x1b, w1b, b1, nullptr,
      hbuf, nullptr, nullptr, nullptr, nullptr, A_, 4*H_, H_);
  // FFN2 split-K/2: BM=128, dbuf, 512 blocks, fp32 partials (no bias)
  k_gemm_db<5,1><<<(A_/128)*(H_/192)*2, 512, 0, stream>>>(hbuf, w2b, nullptr, nullptr,
      nullptr, part, nullptr, nullptr, nullptr, A_, H_, 4*H_);
  // fused reduce + bias + residual(x1b) + LN2 -> xout
  k_ln_ffn2<<<A_/4, 256, 0, stream>>>(part, part + (size_t)A_*H_, b2, x1b,
      ln2g, ln2b, xout);
}

// Round 15
// 292.088 us; speedup vs baseline: 1.0227x; 1.0227x over previous
//
#include <hip/hip_runtime.h>
#include <hip/hip_bf16.h>
#include <math.h>

typedef __bf16 bf16;
typedef __attribute__((ext_vector_type(8))) __bf16 bf16x8;
typedef __attribute__((ext_vector_type(4))) __bf16 bf16x4;
typedef __attribute__((ext_vector_type(4))) float f32x4;

#define B_  16
#define S_  512
#define H_  768
#define NH_ 12
#define HD_ 64
#define A_  (B_*S_)   // 8192 token rows

// async global->LDS, 16B per lane; LDS dest = wave-uniform base + lane*16
__device__ __forceinline__ void gload_lds16(const void* g, void* l) {
  __builtin_amdgcn_global_load_lds((const __attribute__((address_space(1))) void*)g,
                                   (__attribute__((address_space(3))) void*)l, 16, 0, 0);
}

// fast gelu: x*sigmoid(1.595769x(1+0.044715x^2)); |dev| vs erf-gelu <= ~3e-4
__device__ __forceinline__ float gelu_fast(float v) {
  const float u = 1.5957691216057308f * v * (1.0f + 0.044715f * v * v);
  return v / (1.0f + __expf(-u));
}

// =====================================================================================
// Double-buffered GEMM, SINGLE barrier per K-tile (best-known R10 structure).
// BM=128, BN=192, BK=64. 512 threads = 8 waves (2M x 4N). 2 slots = 80KB LDS.
// Stage units issued AFTER each k-step's ds_reads (keeps ds_read->MFMA critical path
// tight; stages fill the MFMA shadow). Boundary vmcnt(0)+barrier only.
// SPLIT: 0 = full K; 1 = split-K/2 (slice = sw&1), partial fp32 -> outF (no bias).
// EPI 0: QKV scatter; EPI 2: fast-gelu->bf16; EPI 4: +resB->bf16; EPI 5: fp32 partial.
// =====================================================================================
template<int EPI, int SPLIT>
__global__ __launch_bounds__(512, 4) void k_gemm_db(
    const bf16* __restrict__ Amat, const bf16* __restrict__ Bt,
    const float* __restrict__ bias, const bf16* __restrict__ resB,
    bf16* __restrict__ outB, float* __restrict__ outF,
    bf16* __restrict__ outQ, bf16* __restrict__ outK, bf16* __restrict__ outVT,
    int M, int N, int Kstride)
{
  constexpr int BN_ = 192, NFRAG = 3, SLOT_E = 8192 + BN_*64, WN = 48;
  __shared__ __align__(16) bf16 LDS[2 * SLOT_E];   // 80 KB
  const int tid = threadIdx.x;
  const int w = tid >> 6, l = tid & 63;
  const int lr = l & 15, hi = l >> 4;
  const int wm = w >> 2, wn = w & 3;

  const int nbx = N / BN_;
  const int cpx = gridDim.x >> 3;
  const int sw  = (blockIdx.x & 7) * cpx + (blockIdx.x >> 3);
  const int tile  = sw >> SPLIT;
  const int slice = sw & ((1 << SPLIT) - 1);
  const int by = tile / nbx, bx = tile - by * nbx;
  const int row0 = by * 128, col0 = bx * BN_;
  const int Klen = Kstride >> SPLIT;
  const int koff = slice * Klen;
  const int NT = Klen / 64;

  auto stage = [&](int t, int u) {
    bf16* slot = LDS + (t & 1) * SLOT_E;
    if (u < 2) {
      const int fc = u*512 + tid;
      const int r = fc >> 3, s = fc & 7;
      const int gs = s ^ (r & 7);
      gload_lds16(Amat + (size_t)(row0 + r)*Kstride + koff + t*64 + gs*8,
                  slot + (size_t)fc*8 - (size_t)l*8);
    } else {
      const int fc = (u-2)*512 + tid;
      const int r = fc >> 3, s = fc & 7;
      const int gs = s ^ (r & 7);
      gload_lds16(Bt + (size_t)(col0 + r)*Kstride + koff + t*64 + gs*8,
                  slot + 8192 + (size_t)fc*8 - (size_t)l*8);
    }
  };

  f32x4 acc[4][NFRAG] = {};

#pragma unroll
  for (int u = 0; u < 5; ++u) stage(0, u);
  asm volatile("s_waitcnt vmcnt(0)" ::: "memory");
  __builtin_amdgcn_s_barrier();

  for (int t = 0; t < NT; ++t) {
    const bf16* slot = LDS + (t & 1) * SLOT_E;
    const bool pre = (t + 1 < NT);

    bf16x8 af[4], bfr[NFRAG];
    // ---- k-step 0 ----
#pragma unroll
    for (int m = 0; m < 4; ++m) {
      const int r = wm*64 + m*16 + lr;
      af[m] = *(const bf16x8*)(slot + r*64 + (hi ^ (r & 7))*8);
    }
#pragma unroll
    for (int n = 0; n < NFRAG; ++n) {
      const int r = wn*WN + n*16 + lr;
      bfr[n] = *(const bf16x8*)(slot + 8192 + r*64 + (hi ^ (r & 7))*8);
    }
    if (pre) { stage(t+1, 0); stage(t+1, 1); stage(t+1, 2); }
    asm volatile("s_waitcnt lgkmcnt(0)" ::: "memory");
    __builtin_amdgcn_sched_barrier(0);
    __builtin_amdgcn_s_setprio(1);
#pragma unroll
    for (int m = 0; m < 4; ++m)
#pragma unroll
      for (int n = 0; n < NFRAG; ++n)
        acc[m][n] = __builtin_amdgcn_mfma_f32_16x16x32_bf16(af[m], bfr[n], acc[m][n], 0, 0, 0);
    __builtin_amdgcn_s_setprio(0);

    // ---- k-step 1 ----
#pragma unroll
    for (int m = 0; m < 4; ++m) {
      const int r = wm*64 + m*16 + lr;
      af[m] = *(const bf16x8*)(slot + r*64 + ((4 + hi) ^ (r & 7))*8);
    }
#pragma unroll
    for (int n = 0; n < NFRAG; ++n) {
      const int r = wn*WN + n*16 + lr;
      bfr[n] = *(const bf16x8*)(slot + 8192 + r*64 + ((4 + hi) ^ (r & 7))*8);
    }
    if (pre) { stage(t+1, 3); stage(t+1, 4); }
    asm volatile("s_waitcnt lgkmcnt(0)" ::: "memory");
    __builtin_amdgcn_sched_barrier(0);
    __builtin_amdgcn_s_setprio(1);
#pragma unroll
    for (int m = 0; m < 4; ++m)
#pragma unroll
      for (int n = 0; n < NFRAG; ++n)
        acc[m][n] = __builtin_amdgcn_mfma_f32_16x16x32_bf16(af[m], bfr[n], acc[m][n], 0, 0, 0);
    __builtin_amdgcn_s_setprio(0);

    // ---- single boundary barrier per tile ----
    if (t < NT - 1) {
      asm volatile("s_waitcnt vmcnt(0)" ::: "memory");
      __builtin_amdgcn_s_barrier();
    }
  }

  // ---- epilogue ----
#pragma unroll
  for (int m = 0; m < 4; ++m) {
#pragma unroll
    for (int n = 0; n < NFRAG; ++n) {
#pragma unroll
      for (int i = 0; i < 4; ++i) {
        const int row = row0 + wm*64 + m*16 + hi*4 + i;
        const int col = col0 + wn*WN + n*16 + lr;
        if constexpr (EPI == 5) {
          __builtin_nontemporal_store(acc[m][n][i],
              outF + (size_t)slice*M*N + (size_t)row*N + col);
        } else if constexpr (EPI == 2) {
          float v = acc[m][n][i] + bias[col];
          outB[(size_t)row*N + col] = (bf16)gelu_fast(v);
        } else if constexpr (EPI == 4) {
          float v = acc[m][n][i] + bias[col];
          v += (float)resB[(size_t)row*N + col];
          outB[(size_t)row*N + col] = (bf16)v;
        } else {
          float v = acc[m][n][i] + bias[col];
          const int b = row >> 9, s = row & 511;
          const int which = col / H_;
          const int hcol = col - which * H_;
          const int h = hcol >> 6, d = hcol & 63;
          const size_t bh = (size_t)b * NH_ + h;
          if (which == 0)      outQ[(bh*S_ + s)*HD_ + d] = (bf16)v;
          else if (which == 1) outK[(bh*S_ + s)*HD_ + d] = (bf16)v;
          else                 outVT[(bh*HD_ + d)*S_ + s] = (bf16)v;
        }
      }
    }
  }
}

// ---------------- fused attention: scores -> softmax -> P (nt, pre-sync) -> PV ------
__global__ __launch_bounds__(256) void k_attn_fused(
    const bf16* __restrict__ Qm, const bf16* __restrict__ Km, const bf16* __restrict__ VT,
    const unsigned char* __restrict__ mask, float* __restrict__ P, bf16* __restrict__ AO)
{
  __shared__ __align__(16) bf16 KVs[512*64];
  const int tid = threadIdx.x, w = tid >> 6, l = tid & 63;
  const int lr = l & 15, hi = l >> 4;
  const int cpx = gridDim.x >> 3;
  const int sw  = (blockIdx.x & 7) * cpx + (blockIdx.x >> 3);
  const int bh = sw >> 3, qt = sw & 7;
  const int b = bh / NH_, h = bh - b * NH_;
  const int swz = (lr & 7) << 4;

  const bf16* Kg = Km + (size_t)bh * S_ * HD_;
#pragma unroll
  for (int rnd = 0; rnd < 16; ++rnd) {
    const int c = rnd*256 + tid;
    const int row = c >> 3, col16 = (c & 7) ^ (row & 7);
    gload_lds16(Kg + row*HD_ + col16*8, KVs + (rnd*4 + w)*512);
  }
  const bf16* qrow_g = Qm + (size_t)bh * S_ * HD_ + (size_t)(qt*64 + w*16 + lr) * HD_;
  bf16x8 qf0 = *(const bf16x8*)(qrow_g + hi*8);
  bf16x8 qf1 = *(const bf16x8*)(qrow_g + 32 + hi*8);
  __syncthreads();

  f32x4 acc[32];
#pragma unroll
  for (int ct = 0; ct < 32; ++ct) acc[ct] = f32x4{0.f,0.f,0.f,0.f};
#pragma unroll
  for (int ct = 0; ct < 32; ++ct) {
    const char* kb = (const char*)(KVs + (ct*16 + lr)*64);
    bf16x8 a0 = *(const bf16x8*)(kb + ((hi*16) ^ swz));
    bf16x8 a1 = *(const bf16x8*)(kb + ((64 + hi*16) ^ swz));
    acc[ct] = __builtin_amdgcn_mfma_f32_16x16x32_bf16(a0, qf0, acc[ct], 0, 0, 0);
    acc[ct] = __builtin_amdgcn_mfma_f32_16x16x32_bf16(a1, qf1, acc[ct], 0, 0, 0);
  }
  __syncthreads();

  const bf16* Vg = VT + (size_t)bh * HD_ * S_;
#pragma unroll
  for (int rnd = 0; rnd < 16; ++rnd) {
    const int c = rnd*256 + tid;
    const int row = c >> 6, col16 = (c & 63) ^ (row & 7);
    gload_lds16(Vg + row*S_ + col16*8, KVs + (rnd*4 + w)*512);
  }

  const unsigned char* mrow = mask + b * S_;
  float mx = -1e30f;
#pragma unroll
  for (int ct = 0; ct < 32; ++ct) {
    const unsigned mk4 = *(const unsigned*)(mrow + ct*16 + hi*4);
#pragma unroll
    for (int i = 0; i < 4; ++i) {
      float v = acc[ct][i] * 0.125f;
      if ((mk4 >> (8*i)) & 0xff) v = -1e30f;
      acc[ct][i] = v;
      mx = fmaxf(mx, v);
    }
  }
  mx = fmaxf(mx, __shfl_xor(mx, 16));
  mx = fmaxf(mx, __shfl_xor(mx, 32));
  float sum = 0.f;
#pragma unroll
  for (int ct = 0; ct < 32; ++ct)
#pragma unroll
    for (int i = 0; i < 4; ++i) { float e = __expf(acc[ct][i] - mx); acc[ct][i] = e; sum += e; }
  sum += __shfl_xor(sum, 16);
  sum += __shfl_xor(sum, 32);
  const float inv = 1.f / sum;

  float* prow = P + ((size_t)bh*S_ + (size_t)qt*64 + w*16 + lr) * S_;
#pragma unroll
  for (int ct = 0; ct < 32; ++ct) {
#pragma unroll
    for (int i = 0; i < 4; ++i) acc[ct][i] *= inv;
    __builtin_nontemporal_store(acc[ct], (f32x4*)(prow + ct*16 + hi*4));
  }
  __syncthreads();   // V staged; P stores overlap PV issue

  f32x4 o[4] = {};
#pragma unroll
  for (int c = 0; c < 16; ++c) {
    bf16x8 pa;
#pragma unroll
    for (int i = 0; i < 4; ++i) { pa[i] = (bf16)acc[2*c][i]; pa[4+i] = (bf16)acc[2*c+1][i]; }
    const int cb0 = (64*c + 8*hi) ^ swz;
    const int cb1 = (64*c + 32 + 8*hi) ^ swz;
#pragma unroll
    for (int nt = 0; nt < 4; ++nt) {
      const char* vb = (const char*)(KVs + (nt*16 + lr)*512);
      bf16x4 v0 = *(const bf16x4*)(vb + cb0);
      bf16x4 v1 = *(const bf16x4*)(vb + cb1);
      bf16x8 vf = {v0[0],v0[1],v0[2],v0[3], v1[0],v1[1],v1[2],v1[3]};
      o[nt] = __builtin_amdgcn_mfma_f32_16x16x32_bf16(pa, vf, o[nt], 0, 0, 0);
    }
  }

  bf16* aorow = AO + ((size_t)(b*S_ + qt*64 + w*16))*H_ + h*HD_;
#pragma unroll
  for (int nt = 0; nt < 4; ++nt)
#pragma unroll
    for (int i = 0; i < 4; ++i)
      aorow[(size_t)(hi*4 + i)*H_ + nt*16 + lr] = (bf16)o[nt][i];
}

// ---------------- LayerNorm over H=768 (bf16 input): one wave per row ---------------
__global__ __launch_bounds__(256) void k_layernorm(
    const bf16* __restrict__ X, const float* __restrict__ g, const float* __restrict__ bta,
    bf16* __restrict__ outB)
{
  const int w = threadIdx.x >> 6, l = threadIdx.x & 63;
  const int row = blockIdx.x * 4 + w;
  const bf16* x = X + (size_t)row * H_;
  float v[12]; float s = 0.f, ss = 0.f;
#pragma unroll
  for (int j = 0; j < 3; ++j) {
    bf16x4 b4 = *(const bf16x4*)(x + l*4 + j*256);
#pragma unroll
    for (int e = 0; e < 4; ++e) {
      const float f = (float)b4[e];
      v[j*4 + e] = f; s += f; ss += f*f;
    }
  }
#pragma unroll
  for (int d = 1; d < 64; d <<= 1) { s += __shfl_xor(s, d); ss += __shfl_xor(ss, d); }
  const float mean = s * (1.f / H_);
  const float var  = ss * (1.f / H_) - mean * mean;
  const float inv  = rsqrtf(var + 1e-5f);
#pragma unroll
  for (int j = 0; j < 3; ++j) {
    const int c = l*4 + j*256;
    const float4 gv = *(const float4*)(g + c);
    const float4 bv = *(const float4*)(bta + c);
    bf16x4 o;
    o[0] = (bf16)((v[j*4+0] - mean)*inv*gv.x + bv.x);
    o[1] = (bf16)((v[j*4+1] - mean)*inv*gv.y + bv.y);
    o[2] = (bf16)((v[j*4+2] - mean)*inv*gv.z + bv.z);
    o[3] = (bf16)((v[j*4+3] - mean)*inv*gv.w + bv.w);
    *(bf16x4*)(outB + (size_t)row*H_ + c) = o;
  }
}

// ---------------- fused split-K reduce + bias + residual + LayerNorm -> xout --------
__global__ __launch_bounds__(256) void k_ln_ffn2(
    const float* __restrict__ p0, const float* __restrict__ p1,
    const float* __restrict__ b2, const bf16* __restrict__ res,
    const float* __restrict__ g, const float* __restrict__ bta,
    float* __restrict__ xout)
{
  const int w = threadIdx.x >> 6, l = threadIdx.x & 63;
  const int row = blockIdx.x * 4 + w;
  const size_t base = (size_t)row * H_;
  float v[12]; float s = 0.f, ss = 0.f;
#pragma unroll
  for (int j = 0; j < 3; ++j) {
    const int c = l*4 + j*256;
    const float4 a0 = *(const float4*)(p0 + base + c);
    const float4 a1 = *(const float4*)(p1 + base + c);
    const float4 bb = *(const float4*)(b2 + c);
    bf16x4 r4 = *(const bf16x4*)(res + base + c);
    v[j*4+0] = a0.x + a1.x + bb.x + (float)r4[0];
    v[j*4+1] = a0.y + a1.y + bb.y + (float)r4[1];
    v[j*4+2] = a0.z + a1.z + bb.z + (float)r4[2];
    v[j*4+3] = a0.w + a1.w + bb.w + (float)r4[3];
#pragma unroll
    for (int e = 0; e < 4; ++e) { s += v[j*4+e]; ss += v[j*4+e]*v[j*4+e]; }
  }
#pragma unroll
  for (int d = 1; d < 64; d <<= 1) { s += __shfl_xor(s, d); ss += __shfl_xor(ss, d); }
  const float mean = s * (1.f / H_);
  const float var  = ss * (1.f / H_) - mean * mean;
  const float inv  = rsqrtf(var + 1e-5f);
#pragma unroll
  for (int j = 0; j < 3; ++j) {
    const int c = l*4 + j*256;
    const float4 gv = *(const float4*)(g + c);
    const float4 bv = *(const float4*)(bta + c);
    f32x4 y;
    y[0] = (v[j*4+0] - mean)*inv*gv.x + bv.x;
    y[1] = (v[j*4+1] - mean)*inv*gv.y + bv.y;
    y[2] = (v[j*4+2] - mean)*inv*gv.z + bv.z;
    y[3] = (v[j*4+3] - mean)*inv*gv.w + bv.w;
    __builtin_nontemporal_store(y, (f32x4*)(xout + base + c));
  }
}

// ---------------- fused fp32 -> bf16 conversions (5 segments, 1 kernel) -------------
#define NB0 (A_*H_/1024)      // 6144
#define NB1 (3*H_*H_/1024)    // 1728
#define NB2 (H_*H_/1024)      // 576
#define NB3 (4*H_*H_/1024)    // 2304
#define NB4 (4*H_*H_/1024)    // 2304
__global__ void k_conv_all(
    const float* __restrict__ s0, bf16* __restrict__ d0,
    const float* __restrict__ s1, bf16* __restrict__ d1,
    const float* __restrict__ s2, bf16* __restrict__ d2,
    const float* __restrict__ s3, bf16* __restrict__ d3,
    const float* __restrict__ s4, bf16* __restrict__ d4)
{
  int b = blockIdx.x;
  const float* src; bf16* dst;
  if      (b < NB0)                   { src = s0; dst = d0; }
  else if ((b -= NB0) < NB1)          { src = s1; dst = d1; }
  else if ((b -= NB1) < NB2)          { src = s2; dst = d2; }
  else if ((b -= NB2) < NB3)          { src = s3; dst = d3; }
  else    { b -= NB3;                   src = s4; dst = d4; }
  const int i = (b * 256 + threadIdx.x) * 4;
  const float4 vv = *(const float4*)(src + i);
  bf16x4 o; o[0]=(bf16)vv.x; o[1]=(bf16)vv.y; o[2]=(bf16)vv.z; o[3]=(bf16)vv.w;
  *(bf16x4*)(dst + i) = o;
}

extern "C" void kernel_launch(void* const* d_in, const int* in_sizes, int n_in,
                              void* d_out, int out_size, void* d_ws, size_t ws_size,
                              hipStream_t stream) {
  const float* x      = (const float*)d_in[0];
  const unsigned char* mask = (const unsigned char*)d_in[1];
  const float* w_qkv  = (const float*)d_in[2];
  const float* b_qkv  = (const float*)d_in[3];
  const float* w_out  = (const float*)d_in[4];
  const float* b_out  = (const float*)d_in[5];
  const float* w1     = (const float*)d_in[6];
  const float* b1     = (const float*)d_in[7];
  const float* w2     = (const float*)d_in[8];
  const float* b2     = (const float*)d_in[9];
  const float* ln1g   = (const float*)d_in[10];
  const float* ln1b   = (const float*)d_in[11];
  const float* ln2g   = (const float*)d_in[12];
  const float* ln2b   = (const float*)d_in[13];

  float* xout = (float*)d_out;                      // [8192, 768]
  float* P    = xout + (size_t)A_ * H_;             // [192, 512, 512] attn weights

  char* ws = (char*)d_ws;
  size_t off = 0;
  auto alloc = [&](size_t bytes) { char* p = ws + off; off += (bytes + 255) & ~255ull; return p; };

  bf16* xb   = (bf16*)alloc((size_t)A_*H_*2);
  bf16* wqkv = (bf16*)alloc((size_t)3*H_*H_*2);
  bf16* wo   = (bf16*)alloc((size_t)H_*H_*2);
  bf16* w1b  = (bf16*)alloc((size_t)4*H_*H_*2);
  bf16* w2b  = (bf16*)alloc((size_t)4*H_*H_*2);
  char* qreg = alloc((size_t)A_*H_*2*4);               // q | k | vt | ao
  bf16* q  = (bf16*)qreg;
  bf16* kb = q  + (size_t)A_*H_;
  bf16* vt = kb + (size_t)A_*H_;
  bf16* ao = vt + (size_t)A_*H_;
  bf16* hbuf = q;                                      // [8192,3072] alias, live after ao consumed
  bf16* y1b = (bf16*)alloc((size_t)A_*H_*2);
  bf16* x1b = (bf16*)alloc((size_t)A_*H_*2);
  float* part = (float*)alloc((size_t)2*A_*H_*4);      // split-K partials (fp32 x2)

  // fused conversions (one kernel)
  k_conv_all<<<NB0+NB1+NB2+NB3+NB4, 256, 0, stream>>>(
      x, xb, w_qkv, wqkv, w_out, wo, w1, w1b, w2, w2b);

  // QKV projection + scatter: BM=128, dbuf, 768 blocks
  k_gemm_db<0,0><<<(A_/128)*(3*H_/192), 512, 0, stream>>>(xb, wqkv, b_qkv, nullptr,
      nullptr, nullptr, q, kb, vt, A_, 3*H_, H_);
  // fused scores + softmax (P -> d_out, nt, pre-sync) + PV -> attn_out (XCD-grouped)
  k_attn_fused<<<B_*NH_*8, 256, 0, stream>>>(q, kb, vt, mask, P, ao);
  // out_proj + residual(xb) -> y1b bf16: BM=128, 256 blocks
  k_gemm_db<4,0><<<(A_/128)*(H_/192), 512, 0, stream>>>(ao, wo, b_out, xb,
      y1b, nullptr, nullptr, nullptr, nullptr, A_, H_, H_);
  k_layernorm<<<A_/4, 256, 0, stream>>>(y1b, ln1g, ln1b, x1b);
  // FFN1 + fast-gelu: BM=128, dbuf, 1024 blocks
  k_gemm_db<2,0><<<(A_/128)*(4*H_/192), 512, 0, stream>>>(x1b, w1b, b1, nullptr,
      hbuf, nullptr, nullptr, nullptr, nullptr, A_, 4*H_, H_);
  // FFN2 split-K/2: BM=128, dbuf, 512 blocks, fp32 partials (no bias)
  k_gemm_db<5,1><<<(A_/128)*(H_/192)*2, 512, 0, stream>>>(hbuf, w2b, nullptr, nullptr,
      nullptr, part, nullptr, nullptr, nullptr, A_, H_, 4*H_);
  // fused reduce + bias + residual(x1b) + LN2 -> xout
  k_ln_ffn2<<<A_/4, 256, 0, stream>>>(part, part + (size_t)A_*H_, b2, x1b,
      ln2g, ln2b, xout);
}